// Round 2
// baseline (776.062 us; speedup 1.0000x reference)
//
#include <hip/hip_runtime.h>
#include <hip/hip_bf16.h>
#include <cstdint>

// TTLinear: y = x @ W^T + bias, W (4096x4096) reconstructed from TT cores,
// then a bf16 MFMA GEMM (128x128 tile, GK=64).
//
// R2 change: B fragments are loaded global->VGPR directly (B n0-slice is
// 1 MB -> L2-resident), eliminating B's LDS staging writes + LDS reads.
// Theory: m97 structure is LDS-pipe-bound (~1150 cyc/iter LDS vs 620 MFMA);
// this drops LDS to ~380 cyc/iter -> MFMA-bound.
//
// ws layout: [0,64MiB) xb bf16, [64MiB,96MiB) Wbt bf16 (N x K), then C01 fp32.

typedef __bf16 bf16x8 __attribute__((ext_vector_type(8)));
typedef float f32x4 __attribute__((ext_vector_type(4)));
typedef unsigned short u16;
typedef u16 u16x8 __attribute__((ext_vector_type(8)));

__device__ __forceinline__ u16 f2bf(float f) {
    unsigned u = __builtin_bit_cast(unsigned, f);
    u += 0x7fffu + ((u >> 16) & 1u);   // round-to-nearest-even
    return (u16)(u >> 16);
}

// ---- kernel 1: x fp32 -> bf16 (8 elems/thread, 16B stores) ----
__global__ void k_cvt(const float* __restrict__ x, u16* __restrict__ xb) {
    long i = (long)blockIdx.x * blockDim.x + threadIdx.x;   // one per 8 floats
    const float4* p = (const float4*)x;
    float4 a = p[2 * i], b = p[2 * i + 1];
    u16x8 o;
    o[0] = f2bf(a.x); o[1] = f2bf(a.y); o[2] = f2bf(a.z); o[3] = f2bf(a.w);
    o[4] = f2bf(b.x); o[5] = f2bf(b.y); o[6] = f2bf(b.z); o[7] = f2bf(b.w);
    ((u16x8*)xb)[i] = o;
}

// ---- kernel 2: C01[o0][o1][i0][i1][b2] = sum_b1 core0[0,o0,i0,b1]*core1[b1,o1,i1,b2]
__global__ void k_c01(const float* __restrict__ c0, const float* __restrict__ c1,
                      float* __restrict__ c01) {
    int idx = blockIdx.x * 256 + threadIdx.x;   // 524288 total
    int b2 = idx & 7, i1 = (idx >> 3) & 15, i0 = (idx >> 7) & 15;
    int o1 = (idx >> 11) & 15, o0 = idx >> 15;
    float s = 0.f;
#pragma unroll
    for (int b1 = 0; b1 < 8; ++b1)
        s += c0[(o0 * 16 + i0) * 8 + b1] * c1[((b1 * 16 + o1) * 16 + i1) * 8 + b2];
    c01[idx] = s;
}

// ---- kernel 3: Wbt[o][i] bf16 (B^T layout, N x K); thread computes 8 consecutive i
__global__ void k_w(const float* __restrict__ c01, const float* __restrict__ c2,
                    u16* __restrict__ wbt) {
    int idx = blockIdx.x * 256 + threadIdx.x;   // 2,097,152 total
    int i2h = idx & 1;
    int i1 = (idx >> 1) & 15;
    int i0 = (idx >> 5) & 15;
    int o = idx >> 9;                            // 0..4095
    int o2 = o & 15, o1 = (o >> 4) & 15, o0 = o >> 8;
    const float* c = &c01[(((o0 * 16 + o1) * 16 + i0) * 16 + i1) * 8];
    float acc[8] = {0, 0, 0, 0, 0, 0, 0, 0};
#pragma unroll
    for (int b2 = 0; b2 < 8; ++b2) {
        float cv = c[b2];
        const float* cc = &c2[(b2 * 16 + o2) * 16 + i2h * 8];
#pragma unroll
        for (int j = 0; j < 8; ++j) acc[j] += cv * cc[j];
    }
    u16x8 ov;
#pragma unroll
    for (int j = 0; j < 8; ++j) ov[j] = f2bf(acc[j]);
    ((u16x8*)wbt)[(long)o * 512 + (i0 * 32 + i1 * 2 + i2h)] = ov;
}

// ---- kernel 4: GEMM. C[m][n] = sum_k A[m,k]*B[n,k] + bias[n] ----
// A staged via global_load_lds (16 KB LDS); B fragments loaded global->VGPR.
#define GM 128
#define GN 128
#define GK 64

__device__ __forceinline__ void gload_lds16(const void* g, void* l) {
    __builtin_amdgcn_global_load_lds(
        (const __attribute__((address_space(1))) unsigned*)g,
        (__attribute__((address_space(3))) unsigned*)l, 16, 0, 0);
}

__global__ void k_gemm(const u16* __restrict__ A, const u16* __restrict__ B,
                       const float* __restrict__ bias, float* __restrict__ C,
                       int M, int N, int K) {
    __shared__ __align__(16) u16 lA[GM * GK];     // 16 KB, A only
    const int t = threadIdx.x;
    const int m0 = blockIdx.y * GM, n0 = blockIdx.x * GN;
    const int wave = t >> 6, lane = t & 63;
    const int wm = (wave >> 1) * 64, wn = (wave & 1) * 64;
    const int lr = lane & 15, quad = lane >> 4;

    f32x4 acc[4][4];
#pragma unroll
    for (int mi = 0; mi < 4; ++mi)
#pragma unroll
        for (int ni = 0; ni < 4; ++ni) acc[mi][ni] = 0.f;

    const int e = t * 8;   // staging elem offset; +2048 per chunk
    // B fragment base: row = n0 + wn + ni*16 + lr, k = k0 + kk2*32 + quad*8
    const u16* Bb = B + (long)(n0 + wn + lr) * K + quad * 8;

    for (int k0 = 0; k0 < K; k0 += GK) {
        // A tile -> LDS (async DMA, 4 chunks of 4 KB)
#pragma unroll
        for (int j = 0; j < 4; ++j) {
            int ee = e + j * 2048;
            int r = ee >> 6, c = ee & 63;
            gload_lds16(&A[(long)(m0 + r) * K + k0 + c], &lA[ee]);
        }
        // B fragments -> VGPR, in flight together with the A DMA; the
        // barrier's vmcnt(0) drain covers both.
        bf16x8 bc[2][4];
#pragma unroll
        for (int kk2 = 0; kk2 < 2; ++kk2)
#pragma unroll
            for (int ni = 0; ni < 4; ++ni)
                bc[kk2][ni] = *(const bf16x8*)(Bb + (long)ni * 16 * K + k0 + kk2 * 32);
        __syncthreads();
#pragma unroll
        for (int kk2 = 0; kk2 < 2; ++kk2) {
            bf16x8 af[4];
#pragma unroll
            for (int i = 0; i < 4; ++i)
                af[i] = *(const bf16x8*)&lA[(wm + i * 16 + lr) * GK + kk2 * 32 + quad * 8];
#pragma unroll
            for (int mi = 0; mi < 4; ++mi)
#pragma unroll
                for (int ni = 0; ni < 4; ++ni)
                    acc[mi][ni] = __builtin_amdgcn_mfma_f32_16x16x32_bf16(
                        af[mi], bc[kk2][ni], acc[mi][ni], 0, 0, 0);
        }
        __syncthreads();
    }

    // epilogue: D row = quad*4 + r (m), col = lr (n); add bias, store fp32
#pragma unroll
    for (int ni = 0; ni < 4; ++ni) {
        int gn = n0 + wn + ni * 16 + lr;
        float bv = bias[gn];
#pragma unroll
        for (int mi = 0; mi < 4; ++mi) {
            int gm = m0 + wm + mi * 16 + quad * 4;
#pragma unroll
            for (int r = 0; r < 4; ++r)
                C[(long)(gm + r) * N + gn] = acc[mi][ni][r] + bv;
        }
    }
}

extern "C" void kernel_launch(void* const* d_in, const int* in_sizes, int n_in,
                              void* d_out, int out_size, void* d_ws, size_t ws_size,
                              hipStream_t stream) {
    const float* x = (const float*)d_in[0];
    const float* c0 = (const float*)d_in[1];
    const float* c1 = (const float*)d_in[2];
    const float* c2 = (const float*)d_in[3];
    const float* bias = (const float*)d_in[4];
    float* out = (float*)d_out;

    const int Mb = 8192, Nf = 4096, Kf = 4096;
    char* ws = (char*)d_ws;
    u16* xb = (u16*)ws;                                       // 67,108,864 B
    u16* wbt = (u16*)(ws + 67108864);                         // 33,554,432 B
    float* c01 = (float*)(ws + 67108864 + 33554432);          //  2,097,152 B

    k_cvt<<<dim3((Mb * Kf / 8) / 256), 256, 0, stream>>>(x, xb);
    k_c01<<<dim3(2048), 256, 0, stream>>>(c0, c1, c01);
    k_w<<<dim3(8192), 256, 0, stream>>>(c01, c2, wbt);
    k_gemm<<<dim3(Nf / GN, Mb / GM), 256, 0, stream>>>(xb, wbt, bias, out, Mb, Nf, Kf);
}

// Round 3
// 472.234 us; speedup vs baseline: 1.6434x; 1.6434x over previous
//
#include <hip/hip_runtime.h>
#include <hip/hip_bf16.h>
#include <cstdint>

// TTLinear: y = x @ W^T + bias, W (4096x4096) reconstructed from TT cores,
// then a bf16 MFMA GEMM (128x128 tile, GK=64).
//
// R3: back to R1's LDS-staged A and B (R2's direct-global B was uncoalesced
// 16B x 64-lane scatter -> 2x regression). New: XOR-swizzled LDS layout to
// kill the 16-way bank conflicts R1 had (SQ_LDS_BANK_CONFLICT 1.0e8 = +12
// cyc per ds_read_b128). 16B chunk c of row r lives at slot (c ^ (r&7));
// global_load_lds stays contiguous/coalesced because we permute the GLOBAL
// address per lane instead of padding LDS (padding breaks the DMA).
//
// ws layout: [0,64MiB) xb bf16, [64MiB,96MiB) Wbt bf16 (N x K), then C01 fp32.

typedef __bf16 bf16x8 __attribute__((ext_vector_type(8)));
typedef float f32x4 __attribute__((ext_vector_type(4)));
typedef unsigned short u16;
typedef u16 u16x8 __attribute__((ext_vector_type(8)));

__device__ __forceinline__ u16 f2bf(float f) {
    unsigned u = __builtin_bit_cast(unsigned, f);
    u += 0x7fffu + ((u >> 16) & 1u);   // round-to-nearest-even
    return (u16)(u >> 16);
}

// ---- kernel 1: x fp32 -> bf16 (8 elems/thread, 16B stores) ----
__global__ void k_cvt(const float* __restrict__ x, u16* __restrict__ xb) {
    long i = (long)blockIdx.x * blockDim.x + threadIdx.x;   // one per 8 floats
    const float4* p = (const float4*)x;
    float4 a = p[2 * i], b = p[2 * i + 1];
    u16x8 o;
    o[0] = f2bf(a.x); o[1] = f2bf(a.y); o[2] = f2bf(a.z); o[3] = f2bf(a.w);
    o[4] = f2bf(b.x); o[5] = f2bf(b.y); o[6] = f2bf(b.z); o[7] = f2bf(b.w);
    ((u16x8*)xb)[i] = o;
}

// ---- kernel 2: C01[o0][o1][i0][i1][b2] = sum_b1 core0[0,o0,i0,b1]*core1[b1,o1,i1,b2]
__global__ void k_c01(const float* __restrict__ c0, const float* __restrict__ c1,
                      float* __restrict__ c01) {
    int idx = blockIdx.x * 256 + threadIdx.x;   // 524288 total
    int b2 = idx & 7, i1 = (idx >> 3) & 15, i0 = (idx >> 7) & 15;
    int o1 = (idx >> 11) & 15, o0 = idx >> 15;
    float s = 0.f;
#pragma unroll
    for (int b1 = 0; b1 < 8; ++b1)
        s += c0[(o0 * 16 + i0) * 8 + b1] * c1[((b1 * 16 + o1) * 16 + i1) * 8 + b2];
    c01[idx] = s;
}

// ---- kernel 3: Wbt[o][i] bf16 (B^T layout, N x K); thread computes 8 consecutive i
__global__ void k_w(const float* __restrict__ c01, const float* __restrict__ c2,
                    u16* __restrict__ wbt) {
    int idx = blockIdx.x * 256 + threadIdx.x;   // 2,097,152 total
    int i2h = idx & 1;
    int i1 = (idx >> 1) & 15;
    int i0 = (idx >> 5) & 15;
    int o = idx >> 9;                            // 0..4095
    int o2 = o & 15, o1 = (o >> 4) & 15, o0 = o >> 8;
    const float* c = &c01[(((o0 * 16 + o1) * 16 + i0) * 16 + i1) * 8];
    float acc[8] = {0, 0, 0, 0, 0, 0, 0, 0};
#pragma unroll
    for (int b2 = 0; b2 < 8; ++b2) {
        float cv = c[b2];
        const float* cc = &c2[(b2 * 16 + o2) * 16 + i2h * 8];
#pragma unroll
        for (int j = 0; j < 8; ++j) acc[j] += cv * cc[j];
    }
    u16x8 ov;
#pragma unroll
    for (int j = 0; j < 8; ++j) ov[j] = f2bf(acc[j]);
    ((u16x8*)wbt)[(long)o * 512 + (i0 * 32 + i1 * 2 + i2h)] = ov;
}

// ---- kernel 4: GEMM. C[m][n] = sum_k A[m,k]*B[n,k] + bias[n] ----
// XOR-swizzled LDS: 16B chunk c of row r stored at slot (c ^ (r & 7)).
#define GM 128
#define GN 128
#define GK 64

__device__ __forceinline__ void gload_lds16(const void* g, void* l) {
    __builtin_amdgcn_global_load_lds(
        (const __attribute__((address_space(1))) unsigned*)g,
        (__attribute__((address_space(3))) unsigned*)l, 16, 0, 0);
}

__global__ void k_gemm(const u16* __restrict__ A, const u16* __restrict__ B,
                       const float* __restrict__ bias, float* __restrict__ C,
                       int M, int N, int K) {
    __shared__ __align__(16) u16 lA[GM * GK];
    __shared__ __align__(16) u16 lB[GN * GK];
    const int t = threadIdx.x;
    const int m0 = blockIdx.y * GM, n0 = blockIdx.x * GN;
    const int wave = t >> 6, lane = t & 63;
    const int wm = (wave >> 1) * 64, wn = (wave & 1) * 64;
    const int lr = lane & 15, quad = lane >> 4;
    const int sw = lr & 7;                       // fragment-read swizzle term

    f32x4 acc[4][4];
#pragma unroll
    for (int mi = 0; mi < 4; ++mi)
#pragma unroll
        for (int ni = 0; ni < 4; ++ni) acc[mi][ni] = 0.f;

    for (int k0 = 0; k0 < K; k0 += GK) {
        // stage A and B tiles -> LDS, swizzled. ci = 16B-chunk index 0..1023;
        // row r = ci>>3, slot = ci&7, global chunk = slot ^ (r&7). The global
        // addresses stay within the same 128B row segment -> coalesced.
#pragma unroll
        for (int j = 0; j < 4; ++j) {
            int ci = j * 256 + t;
            int r = ci >> 3;
            int c = (ci & 7) ^ (r & 7);
            gload_lds16(&A[(long)(m0 + r) * K + k0 + c * 8], &lA[ci * 8]);
        }
#pragma unroll
        for (int j = 0; j < 4; ++j) {
            int ci = j * 256 + t;
            int r = ci >> 3;
            int c = (ci & 7) ^ (r & 7);
            gload_lds16(&B[(long)(n0 + r) * K + k0 + c * 8], &lB[ci * 8]);
        }
        __syncthreads();
#pragma unroll
        for (int kk2 = 0; kk2 < 2; ++kk2) {
            const int sl = ((kk2 * 4 + quad) ^ sw) * 8;   // swizzled chunk offset
            bf16x8 af[4], bfr[4];
#pragma unroll
            for (int i = 0; i < 4; ++i)
                af[i] = *(const bf16x8*)&lA[(wm + i * 16 + lr) * GK + sl];
#pragma unroll
            for (int i = 0; i < 4; ++i)
                bfr[i] = *(const bf16x8*)&lB[(wn + i * 16 + lr) * GK + sl];
#pragma unroll
            for (int mi = 0; mi < 4; ++mi)
#pragma unroll
                for (int ni = 0; ni < 4; ++ni)
                    acc[mi][ni] = __builtin_amdgcn_mfma_f32_16x16x32_bf16(
                        af[mi], bfr[ni], acc[mi][ni], 0, 0, 0);
        }
        __syncthreads();
    }

    // epilogue: D row = quad*4 + r (m), col = lr (n); add bias, store fp32
#pragma unroll
    for (int ni = 0; ni < 4; ++ni) {
        int gn = n0 + wn + ni * 16 + lr;
        float bv = bias[gn];
#pragma unroll
        for (int mi = 0; mi < 4; ++mi) {
            int gm = m0 + wm + mi * 16 + quad * 4;
#pragma unroll
            for (int r = 0; r < 4; ++r)
                C[(long)(gm + r) * N + gn] = acc[mi][ni][r] + bv;
        }
    }
}

extern "C" void kernel_launch(void* const* d_in, const int* in_sizes, int n_in,
                              void* d_out, int out_size, void* d_ws, size_t ws_size,
                              hipStream_t stream) {
    const float* x = (const float*)d_in[0];
    const float* c0 = (const float*)d_in[1];
    const float* c1 = (const float*)d_in[2];
    const float* c2 = (const float*)d_in[3];
    const float* bias = (const float*)d_in[4];
    float* out = (float*)d_out;

    const int Mb = 8192, Nf = 4096, Kf = 4096;
    char* ws = (char*)d_ws;
    u16* xb = (u16*)ws;                                       // 67,108,864 B
    u16* wbt = (u16*)(ws + 67108864);                         // 33,554,432 B
    float* c01 = (float*)(ws + 67108864 + 33554432);          //  2,097,152 B

    k_cvt<<<dim3((Mb * Kf / 8) / 256), 256, 0, stream>>>(x, xb);
    k_c01<<<dim3(2048), 256, 0, stream>>>(c0, c1, c01);
    k_w<<<dim3(8192), 256, 0, stream>>>(c01, c2, wbt);
    k_gemm<<<dim3(Nf / GN, Mb / GM), 256, 0, stream>>>(xb, wbt, bias, out, Mb, Nf, Kf);
}